// Round 11
// baseline (454.966 us; speedup 1.0000x reference)
//
#include <hip/hip_runtime.h>
#include <hip/hip_fp16.h>

#define N_NODES 65536
#define N_EDGES 1048576
#define BUCKET  64   // padded CSR slots per node (deg ~ Poisson(16); P(>64) ~ 1e-18)

typedef float vfloat4 __attribute__((ext_vector_type(4)));
typedef unsigned long long ull;

// ---------------- workspace layout (bytes) ----------------
// counts @ 0x000000   (256 KB)
// dinv   @ 0x040000   (256 KB)
// csr    @ 0x080000   (8 MB, N*64 ushort, zeroed; holes gather row 0, masked)
// xh_lo  @ 0x880000   (4 MB)  fp16 x, features 0..31 (additive term)
// xh_hi  @ 0xC80000   (4 MB)  fp16 x, features 32..63
// tA_lo  @ 0x1080000  (4 MB)  chain state t = dinv .* p, fp16
// tB_lo  @ 0x1480000  (4 MB)
// tA_hi  @ 0x1880000  (4 MB)
// tB_hi  @ 0x1C80000  (4 MB)  -- total 34 MB

// Fused degree-count + CSR scatter. atomicAdd returns the slot. 4 independent
// edge chains per thread (interleaved for coalescing) hide the atomic latency.
__global__ void fused_scatter(const int* __restrict__ src, const int* __restrict__ dst,
                              int* __restrict__ counts, unsigned short* __restrict__ csr) {
    int t = blockIdx.x * blockDim.x + threadIdx.x;
    const int stride = N_EDGES / 4;
    #pragma unroll
    for (int i = 0; i < 4; ++i) {
        int e = t + i * stride;
        int s = src[e];
        int d = dst[e];
        int r = atomicAdd(&counts[d], 1);
        csr[d * BUCKET + r] = (unsigned short)s;
    }
}

__global__ void compute_dinv(const int* __restrict__ counts, float* __restrict__ dinv) {
    int v = blockIdx.x * blockDim.x + threadIdx.x;
    if (v < N_NODES) dinv[v] = rsqrtf((float)(counts[v] + 1));  // +1 self-loop
}

// Build per-chain fp16 tables: t0 = dinv .* x (gather state), xh = x (additive)
__global__ void cvt_x(const float* __restrict__ x, const float* __restrict__ dinv,
                      __half* __restrict__ t0_lo, __half* __restrict__ t0_hi,
                      __half* __restrict__ xh_lo, __half* __restrict__ xh_hi) {
    int i = blockIdx.x * blockDim.x + threadIdx.x;  // i < N*16
    int v = i >> 4;
    int f = i & 15;
    float dv = dinv[v];
    float4 val = ((const float4*)x)[i];
    __half2 xl = __floats2half2_rn(val.x, val.y);
    __half2 xhh = __floats2half2_rn(val.z, val.w);
    ull ox = ((ull)(*(const unsigned*)&xhh) << 32) | (*(const unsigned*)&xl);
    __half2 tl = __floats2half2_rn(dv * val.x, dv * val.y);
    __half2 th = __floats2half2_rn(dv * val.z, dv * val.w);
    ull ot = ((ull)(*(const unsigned*)&th) << 32) | (*(const unsigned*)&tl);
    if (f < 8) {
        ((ull*)xh_lo)[v * 8 + f] = ox;
        ((ull*)t0_lo)[v * 8 + f] = ot;
    } else {
        ((ull*)xh_hi)[v * 8 + (f - 8)] = ox;
        ((ull*)t0_hi)[v * 8 + (f - 8)] = ot;
    }
}

// Dual-chain Horner hop, dinv folded:
//   p_out[d] = sc*dinv[d]*(sum_e t[src_e] + t[d]) + temp[k]*x[d];  t_out = dinv*p_out
// Chains (feature halves) are independent; blockIdx%8<4 -> lo chain (XCDs 0-3),
// else hi chain (XCDs 4-7). Each chain's gather table is 4 MB = one XCD L2 ->
// same-XCD L2 hits. FOUR nodes per wave; lane = 8q+f: q = edge slot 0..7,
// f = feature granule (8 B; 8 lanes = 64 B row = ONE cache line). 8-edge granule
// per node per step -> 32 independent line-gathers in flight per wave. Holes
// gather row 0 (L1-hot), masked via row-select. ushort CSR (2 B/edge).
__global__ void __launch_bounds__(256) hop_kernel(
        const __half* __restrict__ tin_lo, __half* __restrict__ tout_lo,
        const __half* __restrict__ tin_hi, __half* __restrict__ tout_hi,
        const __half* __restrict__ xh_lo, const __half* __restrict__ xh_hi,
        float* __restrict__ out_f32, const float* __restrict__ temp,
        const int* __restrict__ counts, const unsigned short* __restrict__ csr,
        const float* __restrict__ dinv, int k) {
    int b = blockIdx.x;
    int c = (b & 4) ? 1 : 0;                 // chain: 0 = features 0..31, 1 = 32..63
    int l = ((b >> 3) << 2) | (b & 3);       // per-chain block index 0..4095
    int wv = threadIdx.x >> 6;
    int v0 = __builtin_amdgcn_readfirstlane(l * 16 + wv * 4);  // wave-uniform
    int lane = threadIdx.x & 63;
    int q = lane >> 3;   // edge slot 0..7
    int f = lane & 7;    // feature granule (4 fp16 = 8 B)

    const ull* t2 = (const ull*)(c ? tin_hi : tin_lo);
    __half* tout = c ? tout_hi : tout_lo;
    const ull* xh = (const ull*)(c ? xh_hi : xh_lo);

    float tk = temp[k];
    float sc = (k == 1) ? temp[0] : 1.0f;

    int4 cv = *(const int4*)(counts + v0);   // wave-uniform -> s_load_dwordx4
    int cnt[4] = {cv.x, cv.y, cv.z, cv.w};
    float4 dvv = *(const float4*)(dinv + v0);
    float dv[4] = {dvv.x, dvv.y, dvv.z, dvv.w};

    int maxc = max(max(cnt[0], cnt[1]), max(cnt[2], cnt[3]));
    int iters = (maxc + 7) >> 3;   // 8 edges per node per step

    float a0[4] = {0.f, 0.f, 0.f, 0.f};
    float a1[4] = {0.f, 0.f, 0.f, 0.f};
    float a2[4] = {0.f, 0.f, 0.f, 0.f};
    float a3[4] = {0.f, 0.f, 0.f, 0.f};

    #pragma unroll 2
    for (int r = 0; r < iters; ++r) {
        int e0 = r * 8;
        #pragma unroll
        for (int j = 0; j < 4; ++j) {
            // 8 ushort srcs, wave-uniform 16 B -> scalar load
            int4 sg = *(const int4*)(csr + (v0 + j) * BUCKET + e0);
            int sel1 = (q & 2) ? sg.y : sg.x;
            int sel2 = (q & 2) ? sg.w : sg.z;
            int word = (q & 4) ? sel2 : sel1;
            int s = (word >> ((q & 1) * 16)) & 0xffff;   // slot (e0+q)'s src
            ull row = t2[s * 8 + f];                     // one 64 B line per edge
            row = ((e0 + q) < cnt[j]) ? row : 0ull;      // mask holes/overrun
            unsigned rl = (unsigned)row, rh = (unsigned)(row >> 32);
            float2 lo = __half22float2(*(const __half2*)&rl);
            float2 hi = __half22float2(*(const __half2*)&rh);
            a0[j] += lo.x; a1[j] += lo.y; a2[j] += hi.x; a3[j] += hi.y;
        }
    }

    #pragma unroll
    for (int j = 0; j < 4; ++j) {
        a0[j] += __shfl_xor(a0[j], 8); a0[j] += __shfl_xor(a0[j], 16); a0[j] += __shfl_xor(a0[j], 32);
        a1[j] += __shfl_xor(a1[j], 8); a1[j] += __shfl_xor(a1[j], 16); a1[j] += __shfl_xor(a1[j], 32);
        a2[j] += __shfl_xor(a2[j], 8); a2[j] += __shfl_xor(a2[j], 16); a2[j] += __shfl_xor(a2[j], 32);
        a3[j] += __shfl_xor(a3[j], 8); a3[j] += __shfl_xor(a3[j], 16); a3[j] += __shfl_xor(a3[j], 32);
    }

    #pragma unroll
    for (int j = 0; j < 4; ++j) {
        int v = v0 + j;
        ull sx = xh[v * 8 + f];      // additive x term (fp16)
        ull st = t2[v * 8 + f];      // self term t[d]
        unsigned sxl = (unsigned)sx, sxh = (unsigned)(sx >> 32);
        unsigned stl = (unsigned)st, sth = (unsigned)(st >> 32);
        float2 xlo = __half22float2(*(const __half2*)&sxl);
        float2 xhi = __half22float2(*(const __half2*)&sxh);
        float2 slo = __half22float2(*(const __half2*)&stl);
        float2 shi = __half22float2(*(const __half2*)&sth);
        float m = sc * dv[j];
        float r0 = m * (a0[j] + slo.x) + tk * xlo.x;
        float r1 = m * (a1[j] + slo.y) + tk * xlo.y;
        float r2 = m * (a2[j] + shi.x) + tk * xhi.x;
        float r3 = m * (a3[j] + shi.y) + tk * xhi.y;
        if (q == 0) {
            if (k == 9) {
                vfloat4 o = {r0, r1, r2, r3};
                ((vfloat4*)out_f32)[v * 16 + c * 8 + f] = o;
            } else {
                float d2 = dv[j];
                __half2 plo = __floats2half2_rn(d2 * r0, d2 * r1);
                __half2 phi = __floats2half2_rn(d2 * r2, d2 * r3);
                ull o = ((ull)(*(const unsigned*)&phi) << 32) | (*(const unsigned*)&plo);
                ((ull*)tout)[v * 8 + f] = o;
            }
        }
    }
}

extern "C" void kernel_launch(void* const* d_in, const int* in_sizes, int n_in,
                              void* d_out, int out_size, void* d_ws, size_t ws_size,
                              hipStream_t stream) {
    const float* x    = (const float*)d_in[0];
    const float* temp = (const float*)d_in[1];
    const int*   ei   = (const int*)d_in[2];
    const int* src = ei;             // edge_index[0]
    const int* dst = ei + N_EDGES;   // edge_index[1]
    float* out = (float*)d_out;

    char* ws = (char*)d_ws;
    int*            counts = (int*)            (ws + 0x000000);
    float*          dinv   = (float*)          (ws + 0x040000);
    unsigned short* csr    = (unsigned short*) (ws + 0x080000);   // 8 MB
    __half*         xh_lo  = (__half*)         (ws + 0x880000);
    __half*         xh_hi  = (__half*)         (ws + 0xC80000);
    __half*         tA_lo  = (__half*)         (ws + 0x1080000);
    __half*         tB_lo  = (__half*)         (ws + 0x1480000);
    __half*         tA_hi  = (__half*)         (ws + 0x1880000);
    __half*         tB_hi  = (__half*)         (ws + 0x1C80000);

    (void)hipMemsetAsync(counts, 0, N_NODES * sizeof(int), stream);
    (void)hipMemsetAsync(csr, 0, N_NODES * BUCKET * sizeof(unsigned short), stream);

    fused_scatter<<<(N_EDGES / 4) / 256, 256, 0, stream>>>(src, dst, counts, csr);
    compute_dinv<<<N_NODES / 256, 256, 0, stream>>>(counts, dinv);
    cvt_x<<<(N_NODES * 16) / 256, 256, 0, stream>>>(x, dinv, tA_lo, tA_hi, xh_lo, xh_hi);

    // Horner: p = temp[0]*x; for k=1..9: p = A_hat*p + temp[k]*x (scale fused in hop1)
    // Both chains in ONE dispatch; chain tables ping-pong tA -> tB -> tA ...
    const int hop_blocks = 8192;  // 2 chains x 4096; chain = blockIdx%8 < 4 ? lo : hi
    for (int k = 1; k <= 9; ++k) {
        const __half* gi_lo = (k & 1) ? tA_lo : tB_lo;
        __half*       go_lo = (k & 1) ? tB_lo : tA_lo;
        const __half* gi_hi = (k & 1) ? tA_hi : tB_hi;
        __half*       go_hi = (k & 1) ? tB_hi : tA_hi;
        hop_kernel<<<hop_blocks, 256, 0, stream>>>(gi_lo, go_lo, gi_hi, go_hi,
                                                   xh_lo, xh_hi, out, temp,
                                                   counts, csr, dinv, k);
    }
}

// Round 12
// 360.354 us; speedup vs baseline: 1.2626x; 1.2626x over previous
//
#include <hip/hip_runtime.h>
#include <hip/hip_fp16.h>

#define N_NODES 65536
#define N_EDGES 1048576
#define BUCKET  64   // padded CSR slots per node (deg ~ Poisson(16); P(>64) ~ 1e-18)

typedef float vfloat4 __attribute__((ext_vector_type(4)));
typedef unsigned long long ull;

// ---------------- workspace layout (bytes) ----------------
// counts @ 0x000000   (256 KB)
// dinv   @ 0x040000   (256 KB)
// rank   @ 0x080000   (4 MB)
// csr    @ 0x480000   (8 MB, N*64 ushort, zeroed; holes gather row 0, masked)
// xh     @ 0xC80000   (8 MB)  fp16 x (additive Horner term)
// tA     @ 0x1480000  (8 MB)  state t = dinv .* p, fp16
// tB     @ 0x1C80000  (8 MB)  -- total 36.5 MB

__global__ void count_deg(const int* __restrict__ dst, int* __restrict__ counts,
                          int* __restrict__ rank) {
    int e = blockIdx.x * blockDim.x + threadIdx.x;
    if (e < N_EDGES) rank[e] = atomicAdd(&counts[dst[e]], 1);
}

__global__ void compute_dinv(const int* __restrict__ counts, float* __restrict__ dinv) {
    int v = blockIdx.x * blockDim.x + threadIdx.x;
    if (v < N_NODES) dinv[v] = rsqrtf((float)(counts[v] + 1));  // +1 self-loop
}

// pos = d*BUCKET + rank[e]; ushort src (weights folded into the table)
__global__ void scatter_src(const int* __restrict__ src, const int* __restrict__ dst,
                            const int* __restrict__ rank,
                            unsigned short* __restrict__ csr) {
    int e = blockIdx.x * blockDim.x + threadIdx.x;
    if (e >= N_EDGES) return;
    csr[dst[e] * BUCKET + rank[e]] = (unsigned short)src[e];
}

// t0 = fp16(dinv .* x) (gather state), xh = fp16(x) (additive term)
__global__ void cvt_x(const float* __restrict__ x, const float* __restrict__ dinv,
                      __half* __restrict__ t0, __half* __restrict__ xh) {
    int i = blockIdx.x * blockDim.x + threadIdx.x;  // i < N*16
    int v = i >> 4;
    float dv = dinv[v];
    float4 val = ((const float4*)x)[i];
    __half2 xl = __floats2half2_rn(val.x, val.y);
    __half2 xh2 = __floats2half2_rn(val.z, val.w);
    ull ox = ((ull)(*(const unsigned*)&xh2) << 32) | (*(const unsigned*)&xl);
    __half2 tl = __floats2half2_rn(dv * val.x, dv * val.y);
    __half2 th = __floats2half2_rn(dv * val.z, dv * val.w);
    ull ot = ((ull)(*(const unsigned*)&th) << 32) | (*(const unsigned*)&tl);
    ((ull*)xh)[i] = ox;
    ((ull*)t0)[i] = ot;
}

// Horner hop, dinv folded:  p_out[d] = sc*dinv[d]*(sum_e t[src_e] + t[d]) + temp[k]*x[d]
//                           t_out[d] = dinv[d]*p_out[d]  (k<9; k==9 writes p fp32)
// FOUR nodes per wave (v0..v0+3 wave-uniform -> CSR/meta on the scalar pipe).
// lane = 16q+f: q = edge slot 0..3 per granule-of-4, f = feature quad (8 B;
// 16 lanes = 128 B row). 16 edges per node per iter via 4 granules -> 16
// independent row-gathers in flight per wave. ushort CSR: two scalar dwordx4
// loads cover 16 slots. Holes gather row 0 (L1-hot) and are zero-masked.
__global__ void __launch_bounds__(256) hop_kernel(
        const __half* __restrict__ tab, const __half* __restrict__ xh,
        __half* __restrict__ tab_out, float* __restrict__ out_f32,
        const float* __restrict__ temp, const int* __restrict__ counts,
        const unsigned short* __restrict__ csr, const float* __restrict__ dinv,
        int k) {
    int gtid = blockIdx.x * blockDim.x + threadIdx.x;
    int wave = __builtin_amdgcn_readfirstlane(gtid >> 6);
    int lane = gtid & 63;
    int q = lane >> 4;   // edge slot within granule of 4
    int f = lane & 15;   // feature quad

    int v0 = wave * 4;
    float tk = temp[k];
    float sc = (k == 1) ? temp[0] : 1.0f;

    int4 cv = *(const int4*)(counts + v0);     // wave-uniform -> s_load_dwordx4
    int cnt[4] = {cv.x, cv.y, cv.z, cv.w};
    float4 dvv = *(const float4*)(dinv + v0);
    float dv[4] = {dvv.x, dvv.y, dvv.z, dvv.w};

    int maxc = max(max(cnt[0], cnt[1]), max(cnt[2], cnt[3]));
    int iters = (maxc + 15) >> 4;   // 16 edges per node per iteration

    const ull* t2 = (const ull*)tab;   // 8 B granule; row = 16 granules = 128 B
    float a0[4] = {0.f, 0.f, 0.f, 0.f};
    float a1[4] = {0.f, 0.f, 0.f, 0.f};
    float a2[4] = {0.f, 0.f, 0.f, 0.f};
    float a3[4] = {0.f, 0.f, 0.f, 0.f};

    for (int r = 0; r < iters; ++r) {
        int e0 = r * 16;
        #pragma unroll
        for (int j = 0; j < 4; ++j) {
            // 16 ushort srcs = 32 B, wave-uniform -> two scalar dwordx4 loads
            const int4* bp = (const int4*)(csr + (v0 + j) * BUCKET + e0);
            int4 sgA = bp[0];   // slots 0..7
            int4 sgB = bp[1];   // slots 8..15
            #pragma unroll
            for (int g = 0; g < 4; ++g) {
                int4 sg = (g & 2) ? sgB : sgA;
                int word = (g & 1) ? ((q & 2) ? sg.w : sg.z)
                                   : ((q & 2) ? sg.y : sg.x);
                int s = (word >> ((q & 1) * 16)) & 0xffff;   // slot 4g+q's src
                ull row = t2[s * 16 + f];
                row = ((e0 + 4 * g + q) < cnt[j]) ? row : 0ull;  // mask holes
                unsigned rl = (unsigned)row, rh = (unsigned)(row >> 32);
                float2 lo = __half22float2(*(const __half2*)&rl);
                float2 hi = __half22float2(*(const __half2*)&rh);
                a0[j] += lo.x; a1[j] += lo.y; a2[j] += hi.x; a3[j] += hi.y;
            }
        }
    }

    #pragma unroll
    for (int j = 0; j < 4; ++j) {
        a0[j] += __shfl_xor(a0[j], 16); a0[j] += __shfl_xor(a0[j], 32);
        a1[j] += __shfl_xor(a1[j], 16); a1[j] += __shfl_xor(a1[j], 32);
        a2[j] += __shfl_xor(a2[j], 16); a2[j] += __shfl_xor(a2[j], 32);
        a3[j] += __shfl_xor(a3[j], 16); a3[j] += __shfl_xor(a3[j], 32);
    }

    #pragma unroll
    for (int j = 0; j < 4; ++j) {
        int v = v0 + j;
        ull sx = ((const ull*)xh)[v * 16 + f];   // additive x term (fp16)
        ull st = t2[v * 16 + f];                 // self term t[d]
        unsigned sxl = (unsigned)sx, sxh2 = (unsigned)(sx >> 32);
        unsigned stl = (unsigned)st, sth = (unsigned)(st >> 32);
        float2 xlo = __half22float2(*(const __half2*)&sxl);
        float2 xhi = __half22float2(*(const __half2*)&sxh2);
        float2 slo = __half22float2(*(const __half2*)&stl);
        float2 shi = __half22float2(*(const __half2*)&sth);
        float m = sc * dv[j];
        float r0 = m * (a0[j] + slo.x) + tk * xlo.x;
        float r1 = m * (a1[j] + slo.y) + tk * xlo.y;
        float r2 = m * (a2[j] + shi.x) + tk * xhi.x;
        float r3 = m * (a3[j] + shi.y) + tk * xhi.y;
        if (q == 0) {
            if (k == 9) {
                vfloat4 o = {r0, r1, r2, r3};
                ((vfloat4*)out_f32)[v * 16 + f] = o;
            } else {
                float d2 = dv[j];
                __half2 plo = __floats2half2_rn(d2 * r0, d2 * r1);
                __half2 phi = __floats2half2_rn(d2 * r2, d2 * r3);
                ull o = ((ull)(*(const unsigned*)&phi) << 32)
                      | (*(const unsigned*)&plo);
                ((ull*)tab_out)[v * 16 + f] = o;
            }
        }
    }
}

extern "C" void kernel_launch(void* const* d_in, const int* in_sizes, int n_in,
                              void* d_out, int out_size, void* d_ws, size_t ws_size,
                              hipStream_t stream) {
    const float* x    = (const float*)d_in[0];
    const float* temp = (const float*)d_in[1];
    const int*   ei   = (const int*)d_in[2];
    const int* src = ei;             // edge_index[0]
    const int* dst = ei + N_EDGES;   // edge_index[1]
    float* out = (float*)d_out;

    char* ws = (char*)d_ws;
    int*            counts = (int*)            (ws + 0x000000);
    float*          dinv   = (float*)          (ws + 0x040000);
    int*            rank   = (int*)            (ws + 0x080000);
    unsigned short* csr    = (unsigned short*) (ws + 0x480000);   // 8 MB
    __half*         xh     = (__half*)         (ws + 0xC80000);
    __half*         tA     = (__half*)         (ws + 0x1480000);
    __half*         tB     = (__half*)         (ws + 0x1C80000);

    (void)hipMemsetAsync(counts, 0, N_NODES * sizeof(int), stream);
    (void)hipMemsetAsync(csr, 0, N_NODES * BUCKET * sizeof(unsigned short), stream);

    count_deg<<<N_EDGES / 256, 256, 0, stream>>>(dst, counts, rank);
    compute_dinv<<<N_NODES / 256, 256, 0, stream>>>(counts, dinv);
    scatter_src<<<N_EDGES / 256, 256, 0, stream>>>(src, dst, rank, csr);
    cvt_x<<<(N_NODES * 16) / 256, 256, 0, stream>>>(x, dinv, tA, xh);

    // Horner: p = temp[0]*x; for k=1..9: p = A_hat*p + temp[k]*x (scale fused in hop1)
    // Table invariant t_k = dinv .* p_k; ping-pong tA -> tB -> tA ...
    const int hop_blocks = (N_NODES / 4) * 64 / 256;  // 4 nodes per wave
    const __half* gin = tA;
    for (int k = 1; k <= 9; ++k) {
        __half* gout = (k & 1) ? tB : tA;
        hop_kernel<<<hop_blocks, 256, 0, stream>>>(gin, xh, gout, out, temp,
                                                   counts, csr, dinv, k);
        gin = gout;
    }
}